// Round 12
// baseline (576.084 us; speedup 1.0000x reference)
//
#include <hip/hip_runtime.h>
#include <hip/hip_bf16.h>
#include <math.h>

// Problem constants (match reference setup_inputs)
#define NN   100000
#define NE   1600000
#define FIN  128
#define HID  32
#define NHEADS 4
#define NCLS 10

typedef unsigned int uint32;
typedef __fp16 half2_t __attribute__((ext_vector_type(2)));
typedef __fp16 half8_t __attribute__((ext_vector_type(8)));
typedef float  f32x4   __attribute__((ext_vector_type(4)));

// pack 2 fp32 -> packed fp16 pair (v_cvt_pkrtz_f16_f32, 1 inst)
__device__ __forceinline__ uint32 packh2(float a, float b) {
    half2_t h = __builtin_amdgcn_cvt_pkrtz(a, b);
    return __builtin_bit_cast(uint32, h);
}
__device__ __forceinline__ float h_lo(uint32 v) {
    return (float)__builtin_bit_cast(half2_t, v)[0];
}
__device__ __forceinline__ float h_hi(uint32 v) {
    return (float)__builtin_bit_cast(half2_t, v)[1];
}
__device__ __forceinline__ half8_t as_h8(uint4 v) {
    return __builtin_bit_cast(half8_t, v);
}

// ---------------------------------------------------------------------------
// CSR build kernels
// ---------------------------------------------------------------------------
__global__ void zero_i32(int* __restrict__ p, int n) {
    int i = blockIdx.x * blockDim.x + threadIdx.x;
    if (i < n) p[i] = 0;
}

__global__ void hist_rank_kernel(const int* __restrict__ dst, int* __restrict__ cnt,
                                 int* __restrict__ rank, int e) {
    const int t0 = blockIdx.x * (blockDim.x * 4) + threadIdx.x;
    int d[4];
    bool a[4];
#pragma unroll
    for (int k = 0; k < 4; ++k) {
        const int j = t0 + k * 256;
        a[k] = (j < e);
        d[k] = a[k] ? dst[j] : 0;
    }
    int r[4];
#pragma unroll
    for (int k = 0; k < 4; ++k)
        if (a[k]) r[k] = atomicAdd(&cnt[d[k]], 1);
#pragma unroll
    for (int k = 0; k < 4; ++k) {
        const int j = t0 + k * 256;
        if (a[k]) rank[j] = r[k];
    }
}

__global__ void scan_block_sums(const int* __restrict__ cnt, int* __restrict__ bsum, int n) {
    __shared__ int sm[256];
    int i = blockIdx.x * 256 + threadIdx.x;
    int v = (i < n) ? cnt[i] : 0;
    sm[threadIdx.x] = v;
    __syncthreads();
    for (int off = 128; off > 0; off >>= 1) {
        if (threadIdx.x < off) sm[threadIdx.x] += sm[threadIdx.x + off];
        __syncthreads();
    }
    if (threadIdx.x == 0) bsum[blockIdx.x] = sm[0];
}

__global__ void scan_single(const int* __restrict__ bsum, int* __restrict__ boff, int nb) {
    __shared__ int sm[512];
    int t = threadIdx.x;
    int v = (t < nb) ? bsum[t] : 0;
    sm[t] = v;
    __syncthreads();
    for (int off = 1; off < 512; off <<= 1) {
        int u = (t >= off) ? sm[t - off] : 0;
        __syncthreads();
        sm[t] += u;
        __syncthreads();
    }
    if (t < nb) boff[t] = sm[t] - v;   // exclusive
}

__global__ void scan_final(const int* __restrict__ cnt, const int* __restrict__ boff,
                           int* __restrict__ rowptr, int n) {
    __shared__ int sm[256];
    int i = blockIdx.x * 256 + threadIdx.x;
    int v = (i < n) ? cnt[i] : 0;
    sm[threadIdx.x] = v;
    __syncthreads();
    for (int off = 1; off < 256; off <<= 1) {
        int u = (threadIdx.x >= off) ? sm[threadIdx.x - off] : 0;
        __syncthreads();
        sm[threadIdx.x] += u;
        __syncthreads();
    }
    int incl = sm[threadIdx.x];
    int excl = incl - v;
    if (i < n) rowptr[i] = boff[blockIdx.x] + excl;
    if (i == n - 1) rowptr[n] = boff[blockIdx.x] + incl;  // == E
}

__global__ void scatter_kernel(const int* __restrict__ src, const int* __restrict__ dst,
                               const int* __restrict__ rank, const int* __restrict__ rowptr,
                               int* __restrict__ esrc, int e) {
    const int t0 = blockIdx.x * (blockDim.x * 4) + threadIdx.x;
#pragma unroll
    for (int k = 0; k < 4; ++k) {
        const int j = t0 + k * 256;
        if (j < e) {
            const int d = dst[j];
            esrc[rowptr[d] + rank[j]] = src[j];
        }
    }
}

// ---------------------------------------------------------------------------
// conversions: fp32 -> packed fp16
// ---------------------------------------------------------------------------
__global__ void conv_x_kernel(const float* __restrict__ x, uint32* __restrict__ Xh, int n4) {
    int i = blockIdx.x * blockDim.x + threadIdx.x;
    if (i >= n4) return;
    const float4 v = ((const float4*)x)[i];
    ((uint2*)Xh)[i] = make_uint2(packh2(v.x, v.y), packh2(v.z, v.w));
}

// W[k][FOUT] fp32 -> Wt[n][k/2] packed fp16 (transposed). All 3 weights in one launch.
__global__ void conv_w_kernel(const float* __restrict__ W0, const float* __restrict__ W1,
                              const float* __restrict__ W2, uint32* __restrict__ Wt0,
                              uint32* __restrict__ Wt1, uint32* __restrict__ Wt2) {
    int t = blockIdx.x * blockDim.x + threadIdx.x;   // < 8192+8192+2048
    if (t < 8192) {
        const int nn = t >> 6, ku = t & 63;
        Wt0[t] = packh2(W0[(2 * ku) * 128 + nn], W0[(2 * ku + 1) * 128 + nn]);
    } else if (t < 16384) {
        const int l = t - 8192;
        const int nn = l >> 6, ku = l & 63;
        Wt1[l] = packh2(W1[(2 * ku) * 128 + nn], W1[(2 * ku + 1) * 128 + nn]);
    } else if (t < 18432) {
        const int l = t - 16384;
        const int nn = l >> 6, ku = l & 63;
        Wt2[l] = packh2(W2[(2 * ku) * 32 + nn], W2[(2 * ku + 1) * 32 + nn]);
    }
}

// ---------------------------------------------------------------------------
// MFMA GEMM (fp16 in, fp32 acc) + fused attention-logit epilogue.
// Fragment layouts (gfx950 16x16x32, verified m89/m91/m120):
//   A: lane holds A[m=lane&15][k=quad*8+j];  B: B[k=quad*8+j][n=lane&15]
//   D: lane holds D[row=quad*4+reg][col=lane&15]
// ---------------------------------------------------------------------------
template <int FOUT, int H>
__global__ __launch_bounds__(256) void gemm_mfma(const uint32* __restrict__ Xh,
                                                 const uint32* __restrict__ Wt,
                                                 const float* __restrict__ a_s,
                                                 const float* __restrict__ a_d,
                                                 float* __restrict__ alS,
                                                 float* __restrict__ alD,
                                                 uint32* __restrict__ Outh, int n) {
    constexpr int NT = FOUT / 16;            // 8 or 2 n-tiles
    const int wave = threadIdx.x >> 6;
    const int lane = threadIdx.x & 63;
    const int c = lane & 15;                 // D col / A load row / B col
    const int q = lane >> 4;                 // quad
    const int row0 = blockIdx.x * 128 + wave * 32;

    int r0 = row0 + c;
    int r1 = row0 + 16 + c;
    if (r0 >= n) r0 = n - 1;
    if (r1 >= n) r1 = n - 1;

    f32x4 acc[2][NT];
#pragma unroll
    for (int m = 0; m < 2; ++m)
#pragma unroll
        for (int nt = 0; nt < NT; ++nt) acc[m][nt] = (f32x4){0.f, 0.f, 0.f, 0.f};

    const uint4* XU = (const uint4*)Xh;
    const uint4* WU = (const uint4*)Wt;

#pragma unroll
    for (int ks = 0; ks < 4; ++ks) {
        const half8_t a0 = as_h8(XU[(size_t)r0 * 16 + ks * 4 + q]);
        const half8_t a1 = as_h8(XU[(size_t)r1 * 16 + ks * 4 + q]);
#pragma unroll
        for (int nt = 0; nt < NT; ++nt) {
            const half8_t b = as_h8(WU[(nt * 16 + c) * 16 + ks * 4 + q]);
            acc[0][nt] = __builtin_amdgcn_mfma_f32_16x16x32_f16(a0, b, acc[0][nt], 0, 0, 0);
            acc[1][nt] = __builtin_amdgcn_mfma_f32_16x16x32_f16(a1, b, acc[1][nt], 0, 0, 0);
        }
    }

    float asv[NT], adv[NT];
#pragma unroll
    for (int nt = 0; nt < NT; ++nt) {
        asv[nt] = a_s[c + 16 * nt];
        adv[nt] = a_d[c + 16 * nt];
    }

#pragma unroll
    for (int m = 0; m < 2; ++m) {
#pragma unroll
        for (int reg = 0; reg < 4; ++reg) {
            const int grow = row0 + m * 16 + q * 4 + reg;
            const bool ok = (grow < n);
            if constexpr (H == 4) {
                float ps[4], pd[4];
#pragma unroll
                for (int h = 0; h < 4; ++h) {
                    ps[h] = acc[m][2 * h][reg] * asv[2 * h] + acc[m][2 * h + 1][reg] * asv[2 * h + 1];
                    pd[h] = acc[m][2 * h][reg] * adv[2 * h] + acc[m][2 * h + 1][reg] * adv[2 * h + 1];
                }
#pragma unroll
                for (int off = 1; off < 16; off <<= 1) {
#pragma unroll
                    for (int h = 0; h < 4; ++h) {
                        ps[h] += __shfl_xor(ps[h], off);
                        pd[h] += __shfl_xor(pd[h], off);
                    }
                }
                if (c < 4 && ok) {
                    const float vs = (c == 0) ? ps[0] : (c == 1) ? ps[1] : (c == 2) ? ps[2] : ps[3];
                    const float vd = (c == 0) ? pd[0] : (c == 1) ? pd[1] : (c == 2) ? pd[2] : pd[3];
                    alS[(size_t)grow * 4 + c] = vs;
                    alD[(size_t)grow * 4 + c] = vd;
                }
            } else {
                float ps = acc[m][0][reg] * asv[0] + acc[m][1][reg] * asv[1];
                float pd = acc[m][0][reg] * adv[0] + acc[m][1][reg] * adv[1];
#pragma unroll
                for (int off = 1; off < 16; off <<= 1) {
                    ps += __shfl_xor(ps, off);
                    pd += __shfl_xor(pd, off);
                }
                if (c == 0 && ok) {
                    alS[grow] = ps;
                    alD[grow] = pd;
                }
            }
#pragma unroll
            for (int nt = 0; nt < NT; ++nt) {
                const float v = acc[m][nt][reg];
                const float o = __shfl_xor(v, 1);
                if (((c & 1) == 0) && ok) {
                    Outh[(size_t)grow * (FOUT / 2) + nt * 8 + (c >> 1)] = packh2(v, o);
                }
            }
        }
    }
}

// ---------------------------------------------------------------------------
// dual-destination wave aggregation (no-max softmax, fp16 gather) + BN + ELU
//   B16[d][F/2] = fp16( elu(bn( sum_e softmax(e)_e * h[src_e,:] + bias )) )
// Each wave owns TWO destinations (d0=base+0, d1=base+1) with duplicated
// state; their phase-1 gather chains and phase-2 row-gather chains issue
// back-to-back -> 2x memory-level parallelism per wave (avg degree 16 gives
// a single chunk per dst, so without pairing there is no loop-level ILP).
// Phase-2 (H=4): 8 edges/step, wave-uniform src -> readfirstlane -> SGPR
// base + lane offset. Phase-2 (H=1): 4 edges/step via 16-lane groups.
// Logits bounded (|e| <~ 10): exp() without max subtraction is exact softmax.
// Grid: ceil(n/8) blocks (4 waves x 2 dst).
// ---------------------------------------------------------------------------
template <int H, int C>
__global__ __launch_bounds__(256) void gat_aggregate(
    const uint32* __restrict__ Hb,            // fp16-packed h, row = H*C/2 uints
    const int* __restrict__ rowptr, const int* __restrict__ esrc,
    const float* __restrict__ alS, const float* __restrict__ alD,
    const float* __restrict__ bias, const float* __restrict__ gamma,
    const float* __restrict__ beta, const float* __restrict__ bnmean,
    const float* __restrict__ bnvar, uint32* __restrict__ B16, int n) {
    constexpr int F  = H * C;                 // 128 or 32
    constexpr int RW = F / 2;                 // uints per row: 64 or 16
    constexpr int NW = 4;
    __shared__ __align__(16) int   s_src[NW][2][68];
    __shared__ __align__(16) float s_ex[NW][2][H][68];

    const int wave = threadIdx.x >> 6;
    const int lane = threadIdx.x & 63;
    const int d0   = blockIdx.x * (NW * 2) + wave * 2;

    if (lane < 4) {
#pragma unroll
        for (int pp = 0; pp < 2; ++pp) {
            s_src[wave][pp][64 + lane] = 0;
#pragma unroll
            for (int h = 0; h < H; ++h) s_ex[wave][pp][h][64 + lane] = 0.f;
        }
    }
    __builtin_amdgcn_wave_barrier();

    int beg[2], end[2];
    float al_d[2][H], sl[2][H];
#pragma unroll
    for (int pp = 0; pp < 2; ++pp) {
        const int d = d0 + pp;
        const bool v = (d < n);
        beg[pp] = v ? rowptr[d] : 0;
        end[pp] = v ? rowptr[d + 1] : 0;
#pragma unroll
        for (int h = 0; h < H; ++h) {
            al_d[pp][h] = v ? alD[(size_t)d * H + h] : 0.f;
            sl[pp][h]   = 0.f;
        }
    }
    float acc[2][2] = {{0.f, 0.f}, {0.f, 0.f}};   // [pair][lo/hi channel]
    const int head = (H == 4) ? (lane >> 4) : 0;
    int base[2] = {beg[0], beg[1]};

    for (;;) {
        const bool act0 = (base[0] < end[0]);
        const bool act1 = (base[1] < end[1]);
        if (!act0 && !act1) break;

        // ---- phase 1 for both destinations (independent chains) ----
#pragma unroll
        for (int pp = 0; pp < 2; ++pp) {
            if (base[pp] < end[pp]) {
                const int j   = base[pp] + lane;
                const bool a  = (j < end[pp]);
                int sj = 0;
                float ex[H];
                if (a) {
                    sj = esrc[j];
                    if constexpr (H == 4) {
                        float4 av = *(const float4*)(alS + (size_t)sj * 4);
                        float t0 = av.x + al_d[pp][0], t1 = av.y + al_d[pp][1];
                        float t2 = av.z + al_d[pp][2], t3 = av.w + al_d[pp][3];
                        t0 = t0 > 0.f ? t0 : 0.2f * t0;
                        t1 = t1 > 0.f ? t1 : 0.2f * t1;
                        t2 = t2 > 0.f ? t2 : 0.2f * t2;
                        t3 = t3 > 0.f ? t3 : 0.2f * t3;
                        ex[0] = __expf(t0); ex[1] = __expf(t1);
                        ex[2] = __expf(t2); ex[3] = __expf(t3);
                    } else {
                        float t0 = alS[sj] + al_d[pp][0];
                        t0 = t0 > 0.f ? t0 : 0.2f * t0;
                        ex[0] = __expf(t0);
                    }
                } else {
#pragma unroll
                    for (int h = 0; h < H; ++h) ex[h] = 0.f;
                }
#pragma unroll
                for (int h = 0; h < H; ++h) {
                    s_ex[wave][pp][h][lane] = ex[h];
                    sl[pp][h] += ex[h];
                }
                s_src[wave][pp][lane] = sj;
            }
        }
        __builtin_amdgcn_wave_barrier();

        // ---- phase 2 for both destinations ----
#pragma unroll
        for (int pp = 0; pp < 2; ++pp) {
            if (base[pp] < end[pp]) {
                const int cc = min(64, end[pp] - base[pp]);
                if constexpr (H == 4) {
                    const int ccr = (cc + 7) & ~7;
                    for (int jj = 0; jj < ccr; jj += 8) {
                        const int4   sa = *(const int4*)  &s_src[wave][pp][jj];
                        const int4   sb = *(const int4*)  &s_src[wave][pp][jj + 4];
                        const float4 wa = *(const float4*)&s_ex[wave][pp][head][jj];
                        const float4 wb = *(const float4*)&s_ex[wave][pp][head][jj + 4];
                        const int b0 = __builtin_amdgcn_readfirstlane(sa.x);
                        const int b1 = __builtin_amdgcn_readfirstlane(sa.y);
                        const int b2 = __builtin_amdgcn_readfirstlane(sa.z);
                        const int b3 = __builtin_amdgcn_readfirstlane(sa.w);
                        const int b4 = __builtin_amdgcn_readfirstlane(sb.x);
                        const int b5 = __builtin_amdgcn_readfirstlane(sb.y);
                        const int b6 = __builtin_amdgcn_readfirstlane(sb.z);
                        const int b7 = __builtin_amdgcn_readfirstlane(sb.w);
                        const uint32 v0 = Hb[(size_t)b0 * RW + lane];
                        const uint32 v1 = Hb[(size_t)b1 * RW + lane];
                        const uint32 v2 = Hb[(size_t)b2 * RW + lane];
                        const uint32 v3 = Hb[(size_t)b3 * RW + lane];
                        const uint32 v4 = Hb[(size_t)b4 * RW + lane];
                        const uint32 v5 = Hb[(size_t)b5 * RW + lane];
                        const uint32 v6 = Hb[(size_t)b6 * RW + lane];
                        const uint32 v7 = Hb[(size_t)b7 * RW + lane];
                        acc[pp][0] = fmaf(h_lo(v0), wa.x, acc[pp][0]);
                        acc[pp][1] = fmaf(h_hi(v0), wa.x, acc[pp][1]);
                        acc[pp][0] = fmaf(h_lo(v1), wa.y, acc[pp][0]);
                        acc[pp][1] = fmaf(h_hi(v1), wa.y, acc[pp][1]);
                        acc[pp][0] = fmaf(h_lo(v2), wa.z, acc[pp][0]);
                        acc[pp][1] = fmaf(h_hi(v2), wa.z, acc[pp][1]);
                        acc[pp][0] = fmaf(h_lo(v3), wa.w, acc[pp][0]);
                        acc[pp][1] = fmaf(h_hi(v3), wa.w, acc[pp][1]);
                        acc[pp][0] = fmaf(h_lo(v4), wb.x, acc[pp][0]);
                        acc[pp][1] = fmaf(h_hi(v4), wb.x, acc[pp][1]);
                        acc[pp][0] = fmaf(h_lo(v5), wb.y, acc[pp][0]);
                        acc[pp][1] = fmaf(h_hi(v5), wb.y, acc[pp][1]);
                        acc[pp][0] = fmaf(h_lo(v6), wb.z, acc[pp][0]);
                        acc[pp][1] = fmaf(h_hi(v6), wb.z, acc[pp][1]);
                        acc[pp][0] = fmaf(h_lo(v7), wb.w, acc[pp][0]);
                        acc[pp][1] = fmaf(h_hi(v7), wb.w, acc[pp][1]);
                    }
                } else {
                    const int g  = lane >> 4;
                    const int li = lane & 15;
                    for (int jj = 0; jj < cc; jj += 4) {
                        const int   idx = jj + g;              // <= 66, inside pad
                        const int   sj2 = s_src[wave][pp][idx];
                        const float w   = s_ex[wave][pp][0][idx];
                        const uint32 v  = Hb[(size_t)sj2 * RW + li];
                        acc[pp][0] = fmaf(h_lo(v), w, acc[pp][0]);
                        acc[pp][1] = fmaf(h_hi(v), w, acc[pp][1]);
                    }
                }
            }
        }
        __builtin_amdgcn_wave_barrier();
        base[0] += 64;
        base[1] += 64;
    }

    // ---- epilogue per destination ----
#pragma unroll
    for (int pp = 0; pp < 2; ++pp) {
        const int d = d0 + pp;
#pragma unroll
        for (int h = 0; h < H; ++h) {
#pragma unroll
            for (int off = 32; off > 0; off >>= 1) sl[pp][h] += __shfl_xor(sl[pp][h], off);
        }
        float a0 = acc[pp][0], a1 = acc[pp][1];
        float sh;
        if constexpr (H == 4) {
            float a = (head & 1) ? sl[pp][1] : sl[pp][0];
            float b = (head & 1) ? sl[pp][3] : sl[pp][2];
            sh = (head & 2) ? b : a;
        } else {
            sh = sl[pp][0];
            a0 += __shfl_xor(a0, 16); a0 += __shfl_xor(a0, 32);
            a1 += __shfl_xor(a1, 16); a1 += __shfl_xor(a1, 32);
        }
        const float inv = 1.f / (sh + 1e-16f);
        const int li  = (F == 128) ? lane : (lane & 15);
        const int c0 = 2 * li, c1 = 2 * li + 1;
        const bool wr = ((F == 128) || (lane < 16)) && (d < n);
        if (wr) {
            float o0 = a0 * inv, o1 = a1 * inv;
            float y0 = (o0 + bias[c0] - bnmean[c0]) * rsqrtf(bnvar[c0] + 1e-5f) * gamma[c0] + beta[c0];
            float y1 = (o1 + bias[c1] - bnmean[c1]) * rsqrtf(bnvar[c1] + 1e-5f) * gamma[c1] + beta[c1];
            y0 = y0 > 0.f ? y0 : expm1f(y0);
            y1 = y1 > 0.f ? y1 : expm1f(y1);
            B16[(size_t)d * RW + li] = packh2(y0, y1);
        }
    }
}

// ---------------------------------------------------------------------------
// classifier: out[n, 10] = fp16(H3)[n, 32] @ Wc[32, 10] + bc
// ---------------------------------------------------------------------------
__global__ void classifier_kernel(const uint32* __restrict__ H3, const float* __restrict__ Wc,
                                  const float* __restrict__ bc, float* __restrict__ out, int n) {
    int t  = blockIdx.x * blockDim.x + threadIdx.x;
    int ni = t / NCLS, c = t % NCLS;
    if (ni >= n) return;
    const uint32* row = H3 + (size_t)ni * 16;
    float a = bc[c];
#pragma unroll
    for (int u = 0; u < 16; ++u) {
        const uint32 v = row[u];
        a = fmaf(h_lo(v), Wc[(2 * u) * NCLS + c], a);
        a = fmaf(h_hi(v), Wc[(2 * u + 1) * NCLS + c], a);
    }
    out[(size_t)ni * NCLS + c] = a;
}

// ---------------------------------------------------------------------------
// launch
// ---------------------------------------------------------------------------
static inline char* align256(char* p) {
    return (char*)(((uintptr_t)p + 255) & ~(uintptr_t)255);
}

extern "C" void kernel_launch(void* const* d_in, const int* in_sizes, int n_in,
                              void* d_out, int out_size, void* d_ws, size_t ws_size,
                              hipStream_t stream) {
    const float* x  = (const float*)d_in[0];
    const int*   ei = (const int*)d_in[1];
    const int N = in_sizes[0] / FIN;
    const int E = in_sizes[1] / 2;
    const int* src = ei;
    const int* dst = ei + E;

    const float *W0 = (const float*)d_in[2],  *as0 = (const float*)d_in[3],
                *ad0 = (const float*)d_in[4], *b0 = (const float*)d_in[5],
                *g0 = (const float*)d_in[6],  *bt0 = (const float*)d_in[7],
                *m0 = (const float*)d_in[8],  *v0 = (const float*)d_in[9];
    const float *W1 = (const float*)d_in[10], *as1 = (const float*)d_in[11],
                *ad1 = (const float*)d_in[12],*b1 = (const float*)d_in[13],
                *g1 = (const float*)d_in[14], *bt1 = (const float*)d_in[15],
                *m1 = (const float*)d_in[16], *v1 = (const float*)d_in[17];
    const float *W2 = (const float*)d_in[18], *as2 = (const float*)d_in[19],
                *ad2 = (const float*)d_in[20],*b2 = (const float*)d_in[21],
                *g2 = (const float*)d_in[22], *bt2 = (const float*)d_in[23],
                *m2 = (const float*)d_in[24], *v2 = (const float*)d_in[25];
    const float *Wc = (const float*)d_in[26], *bc = (const float*)d_in[27];
    float* out = (float*)d_out;

    // workspace carve
    char* p = (char*)d_ws;
    uint32* Xh  = (uint32*)p;   p = align256(p + (size_t)N * 64 * 4);    // x fp16 (uint each)
    uint32* Ht  = (uint32*)p;   p = align256(p + (size_t)N * 64 * 4);    // gemm out fp16
    uint32* B16 = (uint32*)p;   p = align256(p + (size_t)N * 64 * 4);    // layer act fp16
    uint32* Wt0 = (uint32*)p;   p = align256(p + 8192 * 4);
    uint32* Wt1 = (uint32*)p;   p = align256(p + 8192 * 4);
    uint32* Wt2 = (uint32*)p;   p = align256(p + 2048 * 4);
    float* alS = (float*)p;     p = align256(p + (size_t)N * NHEADS * 4);
    float* alD = (float*)p;     p = align256(p + (size_t)N * NHEADS * 4);
    int* cnt = (int*)p;         p = align256(p + (size_t)N * 4);
    int* rowptr = (int*)p;      p = align256(p + (size_t)(N + 1) * 4);
    int* rank = (int*)p;        p = align256(p + (size_t)E * 4);
    int* esrc = (int*)p;        p = align256(p + (size_t)E * 4);
    int* bsum = (int*)p;        p = align256(p + 512 * 4);
    int* boff = (int*)p;        p = align256(p + 512 * 4);
    (void)ws_size; (void)n_in; (void)out_size;

    const int NB = (N + 255) / 256;
    const int EB4 = (E + 1023) / 1024;   // 4 edges/thread kernels

    // ---- CSR build (once; shared by all 3 layers) ----
    zero_i32<<<NB, 256, 0, stream>>>(cnt, N);
    hist_rank_kernel<<<EB4, 256, 0, stream>>>(dst, cnt, rank, E);
    scan_block_sums<<<NB, 256, 0, stream>>>(cnt, bsum, N);
    scan_single<<<1, 512, 0, stream>>>(bsum, boff, NB);
    scan_final<<<NB, 256, 0, stream>>>(cnt, boff, rowptr, N);
    scatter_kernel<<<EB4, 256, 0, stream>>>(src, dst, rank, rowptr, esrc, E);

    // ---- fp16 conversions ----
    conv_x_kernel<<<(N * 32 + 255) / 256, 256, 0, stream>>>(x, Xh, N * 32);
    conv_w_kernel<<<72, 256, 0, stream>>>(W0, W1, W2, Wt0, Wt1, Wt2);

    const int GB = (N + 127) / 128;
    const int AB = (N + 7) / 8;          // aggregate blocks: 4 waves x 2 dst

    // ---- layer 0 ----
    gemm_mfma<128, 4><<<GB, 256, 0, stream>>>(Xh, Wt0, as0, ad0, alS, alD, Ht, N);
    gat_aggregate<4, 32><<<AB, 256, 0, stream>>>(Ht, rowptr, esrc, alS, alD,
                                                 b0, g0, bt0, m0, v0, B16, N);
    // ---- layer 1 ----
    gemm_mfma<128, 4><<<GB, 256, 0, stream>>>(B16, Wt1, as1, ad1, alS, alD, Ht, N);
    gat_aggregate<4, 32><<<AB, 256, 0, stream>>>(Ht, rowptr, esrc, alS, alD,
                                                 b1, g1, bt1, m1, v1, B16, N);
    // ---- layer 2 (single head, C=32) ----
    gemm_mfma<32, 1><<<GB, 256, 0, stream>>>(B16, Wt2, as2, ad2, alS, alD, Ht, N);
    gat_aggregate<1, 32><<<AB, 256, 0, stream>>>(Ht, rowptr, esrc, alS, alD,
                                                 b2, g2, bt2, m2, v2, B16, N);
    // ---- classifier ----
    classifier_kernel<<<(N * NCLS + 255) / 256, 256, 0, stream>>>(B16, Wc, bc, out, N);
}